// Round 1
// baseline (1335.455 us; speedup 1.0000x reference)
//
#include <hip/hip_runtime.h>

#define NEG_SLOPE 0.2f
#define BN_EPS 1e-5f

// ---------- monotone float <-> uint encoding for atomicMax on floats ----------
__device__ __forceinline__ unsigned int enc_f(float f) {
    unsigned int u = __float_as_uint(f);
    return (u & 0x80000000u) ? ~u : (u | 0x80000000u);
}
__device__ __forceinline__ float dec_f(unsigned int u) {
    return (u & 0x80000000u) ? __uint_as_float(u ^ 0x80000000u)
                             : __uint_as_float(~u);
}

// ---------- fp32 tiled GEMM: C[M,N] = A[M,K] @ B[K,N], row-major ----------
#define BM 64
#define BN 64
#define BK 16
__global__ void gemm_kernel(const float* __restrict__ A, const float* __restrict__ B,
                            float* __restrict__ C, int M, int K, int N) {
    __shared__ float As[BK][BM + 1];
    __shared__ float Bs[BK][BN + 1];
    const int bm = blockIdx.y * BM;
    const int bn = blockIdx.x * BN;
    const int tid = threadIdx.x;           // 256 threads
    const int tr = tid >> 4;               // 0..15
    const int tc = tid & 15;               // 0..15
    float acc[4][4] = {};
    for (int k0 = 0; k0 < K; k0 += BK) {
        // load A tile (BM x BK)
        #pragma unroll
        for (int i = tid; i < BM * BK; i += 256) {
            int m = i / BK, kk = i % BK;
            float v = 0.f;
            int gm = bm + m;
            if (gm < M) v = A[(size_t)gm * K + k0 + kk];
            As[kk][m] = v;
        }
        // load B tile (BK x BN)
        #pragma unroll
        for (int i = tid; i < BK * BN; i += 256) {
            int kk = i / BN, n = i % BN;
            float v = 0.f;
            int gn = bn + n;
            if (gn < N) v = B[(size_t)(k0 + kk) * N + gn];
            Bs[kk][n] = v;
        }
        __syncthreads();
        #pragma unroll
        for (int kk = 0; kk < BK; kk++) {
            float a[4], b[4];
            #pragma unroll
            for (int i = 0; i < 4; i++) a[i] = As[kk][tr * 4 + i];
            #pragma unroll
            for (int j = 0; j < 4; j++) b[j] = Bs[kk][tc * 4 + j];
            #pragma unroll
            for (int i = 0; i < 4; i++)
                #pragma unroll
                for (int j = 0; j < 4; j++)
                    acc[i][j] += a[i] * b[j];
        }
        __syncthreads();
    }
    #pragma unroll
    for (int i = 0; i < 4; i++) {
        int m = bm + tr * 4 + i;
        if (m >= M) continue;
        #pragma unroll
        for (int j = 0; j < 4; j++) {
            int n = bn + tc * 4 + j;
            if (n < N) C[(size_t)m * N + n] = acc[i][j];
        }
    }
}

// ---------- per-node attention scores: es/ed[n,h] = sum_c h[n,h,c]*a[h,c] ----------
__global__ void scores_kernel(const float* __restrict__ h,
                              const float* __restrict__ asrc,
                              const float* __restrict__ adst,
                              float* __restrict__ es, float* __restrict__ ed,
                              int Nn, int H, int C) {
    int idx = blockIdx.x * blockDim.x + threadIdx.x;
    if (idx >= Nn * H) return;
    int n = idx / H, hh = idx % H;
    const float* hp = h + ((size_t)n * H + hh) * C;
    float s = 0.f, d = 0.f;
    for (int c = 0; c < C; c++) {
        float v = hp[c];
        s += v * asrc[hh * C + c];
        d += v * adst[hh * C + c];
    }
    es[idx] = s;
    ed[idx] = d;
}

// ---------- edge pass 1: segment max of leaky_relu scores ----------
__global__ void edge_max_kernel(const int* __restrict__ src, const int* __restrict__ dst,
                                const float* __restrict__ es, const float* __restrict__ ed,
                                unsigned int* __restrict__ amax,
                                int E0, int Etot, int H) {
    int idx = blockIdx.x * blockDim.x + threadIdx.x;
    if (idx >= Etot * H) return;
    int e = idx / H, hh = idx % H;
    int s_, d_;
    if (e < E0) { s_ = src[e]; d_ = dst[e]; } else { s_ = d_ = e - E0; }
    float a = es[s_ * H + hh] + ed[d_ * H + hh];
    a = (a >= 0.f) ? a : NEG_SLOPE * a;
    atomicMax(&amax[d_ * H + hh], enc_f(a));
}

// ---------- edge pass 2: segment sum of exp(alpha - amax) ----------
__global__ void edge_den_kernel(const int* __restrict__ src, const int* __restrict__ dst,
                                const float* __restrict__ es, const float* __restrict__ ed,
                                const unsigned int* __restrict__ amax,
                                float* __restrict__ den,
                                int E0, int Etot, int H) {
    int idx = blockIdx.x * blockDim.x + threadIdx.x;
    if (idx >= Etot * H) return;
    int e = idx / H, hh = idx % H;
    int s_, d_;
    if (e < E0) { s_ = src[e]; d_ = dst[e]; } else { s_ = d_ = e - E0; }
    float a = es[s_ * H + hh] + ed[d_ * H + hh];
    a = (a >= 0.f) ? a : NEG_SLOPE * a;
    float m = dec_f(amax[d_ * H + hh]);
    atomicAdd(&den[d_ * H + hh], expf(a - m));
}

// ---------- edge pass 3: weighted scatter-aggregate ----------
__global__ void edge_agg_kernel(const int* __restrict__ src, const int* __restrict__ dst,
                                const float* __restrict__ es, const float* __restrict__ ed,
                                const unsigned int* __restrict__ amax,
                                const float* __restrict__ den,
                                const float* __restrict__ h,
                                float* __restrict__ agg,
                                int E0, int Etot, int H, int C) {
    const int Dout = H * C;
    long long idx = (long long)blockIdx.x * blockDim.x + threadIdx.x;
    if (idx >= (long long)Etot * Dout) return;
    int e = (int)(idx / Dout);
    int j = (int)(idx % Dout);
    int hh = j / C;
    int s_, d_;
    if (e < E0) { s_ = src[e]; d_ = dst[e]; } else { s_ = d_ = e - E0; }
    float a = es[s_ * H + hh] + ed[d_ * H + hh];
    a = (a >= 0.f) ? a : NEG_SLOPE * a;
    float m = dec_f(amax[d_ * H + hh]);
    float ex = expf(a - m);
    float attn = ex / (den[d_ * H + hh] + 1e-16f);
    atomicAdd(&agg[(size_t)d_ * Dout + j], h[(size_t)s_ * Dout + j] * attn);
}

// ---------- epilogue: bias + (ELU) + BN, in place ----------
__global__ void finish_kernel(float* __restrict__ agg,
                              const float* __restrict__ bias,
                              const float* __restrict__ g, const float* __restrict__ be,
                              const float* __restrict__ rm, const float* __restrict__ rv,
                              int Nn, int Dout, int do_elu) {
    int idx = blockIdx.x * blockDim.x + threadIdx.x;
    if (idx >= Nn * Dout) return;
    int j = idx % Dout;
    float y = agg[idx] + bias[j];
    if (do_elu) y = (y > 0.f) ? y : expm1f(y);
    y = (y - rm[j]) * rsqrtf(rv[j] + BN_EPS) * g[j] + be[j];
    agg[idx] = y;
}

extern "C" void kernel_launch(void* const* d_in, const int* in_sizes, int n_in,
                              void* d_out, int out_size, void* d_ws, size_t ws_size,
                              hipStream_t stream) {
    const float* x = (const float*)d_in[0];
    const int* src = (const int*)d_in[1];
    const int* dst = (const int*)d_in[2];
    const int Nn = in_sizes[0] / 128;   // 50000
    const int E0 = in_sizes[1];         // 400000
    const int Etot = E0 + Nn;           // self-loops appended

    // workspace layout
    float* B0 = (float*)d_ws;                       // N*256
    float* B1 = B0 + (size_t)Nn * 256;              // N*256
    float* es = B1 + (size_t)Nn * 256;              // N*8
    float* ed = es + (size_t)Nn * 8;                // N*8
    unsigned int* amax = (unsigned int*)(ed + (size_t)Nn * 8); // N*8
    float* den = (float*)(amax + (size_t)Nn * 8);   // N*8

    const int   din_l[4] = {128, 256, 128, 64};
    const int   H_l[4]   = {8, 8, 8, 1};
    const int   C_l[4]   = {32, 16, 8, 16};
    const float* in_l[4] = { x, B1, B0 + (size_t)Nn * 128, B1 + (size_t)Nn * 64 };
    float* h_l[4]   = { B0, B0, B1, B0 };
    float* agg_l[4] = { B1, B0 + (size_t)Nn * 128, B1 + (size_t)Nn * 64, (float*)d_out };

    for (int l = 0; l < 4; l++) {
        const int din = din_l[l], H = H_l[l], C = C_l[l];
        const int Dout = H * C;
        const float* const* p = (const float* const*)(d_in + 3 + l * 8);
        const float* W    = p[0];
        const float* asrc = p[1];
        const float* adst = p[2];
        const float* bias = p[3];
        const float* g    = p[4];
        const float* be   = p[5];
        const float* rm   = p[6];
        const float* rv   = p[7];
        const float* in = in_l[l];
        float* h   = h_l[l];
        float* agg = agg_l[l];

        // 1. h = in @ W
        dim3 gb((Dout + BN - 1) / BN, (Nn + BM - 1) / BM);
        gemm_kernel<<<gb, 256, 0, stream>>>(in, W, h, Nn, din, Dout);

        // 2. per-node scores
        int t1 = Nn * H;
        scores_kernel<<<(t1 + 255) / 256, 256, 0, stream>>>(h, asrc, adst, es, ed, Nn, H, C);

        // 3. zero accumulators (amax=0 encodes "-inf" under enc_f ordering)
        hipMemsetAsync(amax, 0, sizeof(unsigned int) * (size_t)Nn * H, stream);
        hipMemsetAsync(den, 0, sizeof(float) * (size_t)Nn * H, stream);
        hipMemsetAsync(agg, 0, sizeof(float) * (size_t)Nn * Dout, stream);

        // 4-6. edge passes
        int te = Etot * H;
        edge_max_kernel<<<(te + 255) / 256, 256, 0, stream>>>(src, dst, es, ed, amax, E0, Etot, H);
        edge_den_kernel<<<(te + 255) / 256, 256, 0, stream>>>(src, dst, es, ed, amax, den, E0, Etot, H);
        long long ta = (long long)Etot * Dout;
        edge_agg_kernel<<<(int)((ta + 255) / 256), 256, 0, stream>>>(src, dst, es, ed, amax, den, h, agg,
                                                                     E0, Etot, H, C);

        // 7. bias + ELU + BN
        int tf = Nn * Dout;
        finish_kernel<<<(tf + 255) / 256, 256, 0, stream>>>(agg, bias, g, be, rm, rv, Nn, Dout,
                                                            (l < 3) ? 1 : 0);
    }
}

// Round 2
// 709.216 us; speedup vs baseline: 1.8830x; 1.8830x over previous
//
#include <hip/hip_runtime.h>

#define NEG_SLOPE 0.2f
#define BN_EPS 1e-5f

// ---------- fp32 tiled GEMM: C[M,N] = A[M,K] @ B[K,N], row-major ----------
#define BM 64
#define BN 64
#define BK 16
__global__ void gemm_kernel(const float* __restrict__ A, const float* __restrict__ B,
                            float* __restrict__ C, int M, int K, int N) {
    __shared__ float As[BK][BM + 1];
    __shared__ float Bs[BK][BN + 1];
    const int bm = blockIdx.y * BM;
    const int bn = blockIdx.x * BN;
    const int tid = threadIdx.x;           // 256 threads
    const int tr = tid >> 4;               // 0..15
    const int tc = tid & 15;               // 0..15
    float acc[4][4] = {};
    for (int k0 = 0; k0 < K; k0 += BK) {
        #pragma unroll
        for (int i = tid; i < BM * BK; i += 256) {
            int m = i / BK, kk = i % BK;
            float v = 0.f;
            int gm = bm + m;
            if (gm < M) v = A[(size_t)gm * K + k0 + kk];
            As[kk][m] = v;
        }
        #pragma unroll
        for (int i = tid; i < BK * BN; i += 256) {
            int kk = i / BN, n = i % BN;
            float v = 0.f;
            int gn = bn + n;
            if (gn < N) v = B[(size_t)(k0 + kk) * N + gn];
            Bs[kk][n] = v;
        }
        __syncthreads();
        #pragma unroll
        for (int kk = 0; kk < BK; kk++) {
            float a[4], b[4];
            #pragma unroll
            for (int i = 0; i < 4; i++) a[i] = As[kk][tr * 4 + i];
            #pragma unroll
            for (int j = 0; j < 4; j++) b[j] = Bs[kk][tc * 4 + j];
            #pragma unroll
            for (int i = 0; i < 4; i++)
                #pragma unroll
                for (int j = 0; j < 4; j++)
                    acc[i][j] += a[i] * b[j];
        }
        __syncthreads();
    }
    #pragma unroll
    for (int i = 0; i < 4; i++) {
        int m = bm + tr * 4 + i;
        if (m >= M) continue;
        #pragma unroll
        for (int j = 0; j < 4; j++) {
            int n = bn + tc * 4 + j;
            if (n < N) C[(size_t)m * N + n] = acc[i][j];
        }
    }
}

// ---------- per-node attention scores ----------
__global__ void scores_kernel(const float* __restrict__ h,
                              const float* __restrict__ asrc,
                              const float* __restrict__ adst,
                              float* __restrict__ es, float* __restrict__ ed,
                              int Nn, int H, int C) {
    int idx = blockIdx.x * blockDim.x + threadIdx.x;
    if (idx >= Nn * H) return;
    int n = idx / H, hh = idx % H;
    const float* hp = h + ((size_t)n * H + hh) * C;
    float s = 0.f, d = 0.f;
    for (int c = 0; c < C; c++) {
        float v = hp[c];
        s += v * asrc[hh * C + c];
        d += v * adst[hh * C + c];
    }
    es[idx] = s;
    ed[idx] = d;
}

// ---------- CSR build: histogram -> scan -> scatter ----------
__global__ void hist_kernel(const int* __restrict__ dst, int* __restrict__ counts,
                            int E0, int Etot) {
    int e = blockIdx.x * blockDim.x + threadIdx.x;
    if (e >= Etot) return;
    int d_ = (e < E0) ? dst[e] : e - E0;
    atomicAdd(&counts[d_], 1);
}

__global__ void scan_kernel(const int* __restrict__ counts, int* __restrict__ row_ptr, int Nn) {
    // single block, 1024 threads: chunked exclusive scan with wave-level shfl scans
    __shared__ int wsum[16];
    __shared__ int chunk_total;
    __shared__ int carry_s;
    const int tid = threadIdx.x;
    const int lane = tid & 63;
    const int wid = tid >> 6;
    if (tid == 0) carry_s = 0;
    __syncthreads();
    for (int base = 0; base < Nn; base += 1024) {
        int i = base + tid;
        int v = (i < Nn) ? counts[i] : 0;
        int iv = v;
        #pragma unroll
        for (int off = 1; off < 64; off <<= 1) {
            int t = __shfl_up(iv, off, 64);
            if (lane >= off) iv += t;
        }
        if (lane == 63) wsum[wid] = iv;
        __syncthreads();
        if (tid == 0) {
            int s = 0;
            #pragma unroll
            for (int k = 0; k < 16; k++) { int t = wsum[k]; wsum[k] = s; s += t; }
            chunk_total = s;
        }
        __syncthreads();
        if (i < Nn) row_ptr[i] = carry_s + wsum[wid] + (iv - v);
        __syncthreads();
        if (tid == 0) carry_s += chunk_total;
        __syncthreads();
    }
    if (tid == 0) row_ptr[Nn] = carry_s;
}

__global__ void scatter_kernel(const int* __restrict__ src, const int* __restrict__ dst,
                               int* __restrict__ cursor, int* __restrict__ col,
                               int E0, int Etot) {
    int e = blockIdx.x * blockDim.x + threadIdx.x;
    if (e >= Etot) return;
    int d_ = (e < E0) ? dst[e] : e - E0;
    int s_ = (e < E0) ? src[e] : e - E0;
    int pos = atomicAdd(&cursor[d_], 1);
    col[pos] = s_;
}

// ---------- per-(node,head) segment max over CSR ----------
__global__ void amax_kernel(const int* __restrict__ row_ptr, const int* __restrict__ col,
                            const float* __restrict__ es, const float* __restrict__ ed,
                            float* __restrict__ amax, int Nn, int H) {
    int idx = blockIdx.x * blockDim.x + threadIdx.x;
    if (idx >= Nn * H) return;
    int n = idx / H, hh = idx - n * H;
    float edv = ed[idx];
    float m = -3.4e38f;
    int jb = row_ptr[n], je = row_ptr[n + 1];
    for (int j = jb; j < je; j++) {
        float a = es[col[j] * H + hh] + edv;
        a = (a >= 0.f) ? a : NEG_SLOPE * a;
        m = fmaxf(m, a);
    }
    amax[idx] = m;
}

// ---------- fused softmax + aggregate + bias + ELU + BN ----------
template<int H, int C, int NT, int DO_ELU>
__launch_bounds__(256)
__global__ void gat_aggregate(const int* __restrict__ row_ptr, const int* __restrict__ col,
                              const float* __restrict__ es, const float* __restrict__ ed,
                              const float* __restrict__ amax,
                              const float* __restrict__ h, float* __restrict__ out,
                              const float* __restrict__ bias, const float* __restrict__ g,
                              const float* __restrict__ be, const float* __restrict__ rm,
                              const float* __restrict__ rv, int Nn) {
    constexpr int Dout = H * C;
    constexpr int VEC = Dout / NT;       // channels per thread
    int gt = blockIdx.x * blockDim.x + threadIdx.x;
    int node = gt / NT;
    int t = gt % NT;
    if (node >= Nn) return;
    const int c0 = t * VEC;
    const int hh = c0 / C;
    const float edv = ed[node * H + hh];
    const float m  = amax[node * H + hh];
    float acc[VEC] = {};
    float den = 0.f;
    const int jb = row_ptr[node], je = row_ptr[node + 1];
    for (int j = jb; j < je; j++) {
        const int s = col[j];
        float a = es[s * H + hh] + edv;
        a = (a >= 0.f) ? a : NEG_SLOPE * a;
        const float ex = __expf(a - m);
        den += ex;
        const float* hp = h + (size_t)s * Dout + c0;
        if constexpr (VEC == 4) {
            const float4 hv = *reinterpret_cast<const float4*>(hp);
            acc[0] += ex * hv.x; acc[1] += ex * hv.y;
            acc[2] += ex * hv.z; acc[3] += ex * hv.w;
        } else if constexpr (VEC == 2) {
            const float2 hv = *reinterpret_cast<const float2*>(hp);
            acc[0] += ex * hv.x; acc[1] += ex * hv.y;
        } else {
            acc[0] += ex * hp[0];
        }
    }
    const float inv = 1.f / (den + 1e-16f);
    #pragma unroll
    for (int v = 0; v < VEC; v++) {
        const int jc = c0 + v;
        float y = acc[v] * inv + bias[jc];
        if (DO_ELU) y = (y > 0.f) ? y : expm1f(y);
        y = (y - rm[jc]) * rsqrtf(rv[jc] + BN_EPS) * g[jc] + be[jc];
        out[(size_t)node * Dout + jc] = y;
    }
}

extern "C" void kernel_launch(void* const* d_in, const int* in_sizes, int n_in,
                              void* d_out, int out_size, void* d_ws, size_t ws_size,
                              hipStream_t stream) {
    const float* x = (const float*)d_in[0];
    const int* src = (const int*)d_in[1];
    const int* dst = (const int*)d_in[2];
    const int Nn = in_sizes[0] / 128;   // 50000
    const int E0 = in_sizes[1];         // 400000
    const int Etot = E0 + Nn;           // self-loops appended

    // workspace layout
    float* B0 = (float*)d_ws;                       // N*256
    float* B1 = B0 + (size_t)Nn * 256;              // N*256
    float* es = B1 + (size_t)Nn * 256;              // N*8
    float* ed = es + (size_t)Nn * 8;                // N*8
    float* amax = ed + (size_t)Nn * 8;              // N*8
    int* row_ptr = (int*)(amax + (size_t)Nn * 8);   // N+1
    int* cursor  = row_ptr + (Nn + 1);              // N
    int* col     = cursor + Nn;                     // Etot

    // ---- CSR build (per call; scatter order nondeterministic but fp-tolerable) ----
    hipMemsetAsync(cursor, 0, sizeof(int) * Nn, stream);  // reuse cursor as counts
    hist_kernel<<<(Etot + 255) / 256, 256, 0, stream>>>(dst, cursor, E0, Etot);
    scan_kernel<<<1, 1024, 0, stream>>>(cursor, row_ptr, Nn);
    hipMemcpyAsync(cursor, row_ptr, sizeof(int) * Nn, hipMemcpyDeviceToDevice, stream);
    scatter_kernel<<<(Etot + 255) / 256, 256, 0, stream>>>(src, dst, cursor, col, E0, Etot);

    const int   din_l[4] = {128, 256, 128, 64};
    const int   H_l[4]   = {8, 8, 8, 1};
    const int   C_l[4]   = {32, 16, 8, 16};
    const float* in_l[4] = { x, B1, B0 + (size_t)Nn * 128, B1 + (size_t)Nn * 64 };
    float* h_l[4]   = { B0, B0, B1, B0 };
    float* agg_l[4] = { B1, B0 + (size_t)Nn * 128, B1 + (size_t)Nn * 64, (float*)d_out };

    for (int l = 0; l < 4; l++) {
        const int din = din_l[l], H = H_l[l], C = C_l[l];
        const int Dout = H * C;
        const float* const* p = (const float* const*)(d_in + 3 + l * 8);
        const float* W    = p[0];
        const float* asrc = p[1];
        const float* adst = p[2];
        const float* bias = p[3];
        const float* g    = p[4];
        const float* be   = p[5];
        const float* rm   = p[6];
        const float* rv   = p[7];
        const float* in = in_l[l];
        float* h   = h_l[l];
        float* agg = agg_l[l];

        // 1. h = in @ W
        dim3 gb((Dout + BN - 1) / BN, (Nn + BM - 1) / BM);
        gemm_kernel<<<gb, 256, 0, stream>>>(in, W, h, Nn, din, Dout);

        // 2. per-node scores
        int t1 = Nn * H;
        scores_kernel<<<(t1 + 255) / 256, 256, 0, stream>>>(h, asrc, adst, es, ed, Nn, H, C);

        // 3. per-(node,head) max
        amax_kernel<<<(t1 + 255) / 256, 256, 0, stream>>>(row_ptr, col, es, ed, amax, Nn, H);

        // 4. fused softmax + aggregate + epilogue
        if (l == 0) {
            int total = Nn * 64;
            gat_aggregate<8, 32, 64, 1><<<(total + 255) / 256, 256, 0, stream>>>(
                row_ptr, col, es, ed, amax, h, agg, bias, g, be, rm, rv, Nn);
        } else if (l == 1) {
            int total = Nn * 64;
            gat_aggregate<8, 16, 64, 1><<<(total + 255) / 256, 256, 0, stream>>>(
                row_ptr, col, es, ed, amax, h, agg, bias, g, be, rm, rv, Nn);
        } else if (l == 2) {
            int total = Nn * 64;
            gat_aggregate<8, 8, 64, 1><<<(total + 255) / 256, 256, 0, stream>>>(
                row_ptr, col, es, ed, amax, h, agg, bias, g, be, rm, rv, Nn);
        } else {
            int total = Nn * 16;
            gat_aggregate<1, 16, 16, 0><<<(total + 255) / 256, 256, 0, stream>>>(
                row_ptr, col, es, ed, amax, h, agg, bias, g, be, rm, rv, Nn);
        }
    }
}

// Round 4
// 482.315 us; speedup vs baseline: 2.7688x; 1.4704x over previous
//
#include <hip/hip_runtime.h>

#define NEG_SLOPE 0.2f
#define BN_EPS 1e-5f

// ================= fp32 GEMM, 128 x (16*TN) tile, BK=32, 8x TN per thread ==========
// TN=8 -> BN=128 (for N=256,128) ; TN=4 -> BN=64 (for N=64)
template<int TN>
__launch_bounds__(256)
__global__ void gemm_tile(const float* __restrict__ A, const float* __restrict__ B,
                          float* __restrict__ C, int M, int K, int N) {
    constexpr int BNt = 16 * TN;
    __shared__ float As[32][132];        // transposed: As[kk][m]
    __shared__ float Bs[32][BNt + 4];
    const int bm = blockIdx.y * 128;
    const int bn = blockIdx.x * BNt;
    const int tid = threadIdx.x;
    const int tr = tid >> 4;             // 0..15
    const int tc = tid & 15;             // 0..15
    const int la_m = tid >> 3;           // 0..31
    const int la_k = (tid & 7) << 2;     // 0,4,..,28
    const int lb_row = tid / (BNt / 4);
    const int lb_c = (tid % (BNt / 4)) * 4;
    float acc[8][TN] = {};
    for (int k0 = 0; k0 < K; k0 += 32) {
        #pragma unroll
        for (int p = 0; p < 4; p++) {
            int m = la_m + p * 32;
            int gm = bm + m;
            float4 v = make_float4(0.f, 0.f, 0.f, 0.f);
            if (gm < M) v = *reinterpret_cast<const float4*>(&A[(size_t)gm * K + k0 + la_k]);
            As[la_k + 0][m] = v.x;
            As[la_k + 1][m] = v.y;
            As[la_k + 2][m] = v.z;
            As[la_k + 3][m] = v.w;
        }
        #pragma unroll
        for (int p = 0; p < BNt / 32; p++) {
            int kk = lb_row + p * (1024 / BNt);
            *reinterpret_cast<float4*>(&Bs[kk][lb_c]) =
                *reinterpret_cast<const float4*>(&B[(size_t)(k0 + kk) * N + bn + lb_c]);
        }
        __syncthreads();
        #pragma unroll
        for (int kk = 0; kk < 32; kk++) {
            float a[8], b[TN];
            float4 a0 = *reinterpret_cast<const float4*>(&As[kk][tr * 4]);
            float4 a1 = *reinterpret_cast<const float4*>(&As[kk][64 + tr * 4]);
            a[0] = a0.x; a[1] = a0.y; a[2] = a0.z; a[3] = a0.w;
            a[4] = a1.x; a[5] = a1.y; a[6] = a1.z; a[7] = a1.w;
            float4 b0 = *reinterpret_cast<const float4*>(&Bs[kk][tc * 4]);
            b[0] = b0.x; b[1] = b0.y; b[2] = b0.z; b[3] = b0.w;
            if constexpr (TN == 8) {
                float4 b1 = *reinterpret_cast<const float4*>(&Bs[kk][64 + tc * 4]);
                b[4] = b1.x; b[5] = b1.y; b[6] = b1.z; b[7] = b1.w;
            }
            #pragma unroll
            for (int i = 0; i < 8; i++)
                #pragma unroll
                for (int j = 0; j < TN; j++)
                    acc[i][j] += a[i] * b[j];
        }
        __syncthreads();
    }
    #pragma unroll
    for (int i = 0; i < 8; i++) {
        int m = bm + ((i < 4) ? (tr * 4 + i) : (64 + tr * 4 + (i - 4)));
        if (m >= M) continue;
        float4 v0 = make_float4(acc[i][0], acc[i][1], acc[i][2], acc[i][3]);
        *reinterpret_cast<float4*>(&C[(size_t)m * N + bn + tc * 4]) = v0;
        if constexpr (TN == 8) {
            float4 v1 = make_float4(acc[i][4], acc[i][5], acc[i][6], acc[i][7]);
            *reinterpret_cast<float4*>(&C[(size_t)m * N + bn + 64 + tc * 4]) = v1;
        }
    }
}

// ================= small GEMM for layer 4: K=64, N=16 =================
__launch_bounds__(256)
__global__ void gemm_k64n16(const float* __restrict__ A, const float* __restrict__ B,
                            float* __restrict__ C, int M) {
    __shared__ float As[64][68];
    __shared__ float Bs[64][16];
    const int tid = threadIdx.x;
    const int bm = blockIdx.x * 64;
    {
        int r = tid >> 2, c = (tid & 3) << 2;
        *reinterpret_cast<float4*>(&Bs[r][c]) = *reinterpret_cast<const float4*>(&B[r * 16 + c]);
    }
    #pragma unroll
    for (int p = 0; p < 4; p++) {
        int m = (tid >> 4) + p * 16;
        int c = (tid & 15) << 2;
        int gm = bm + m;
        float4 v = make_float4(0.f, 0.f, 0.f, 0.f);
        if (gm < M) v = *reinterpret_cast<const float4*>(&A[(size_t)gm * 64 + c]);
        *reinterpret_cast<float4*>(&As[m][c]) = v;
    }
    __syncthreads();
    const int tc = tid & 15;
    const int r0 = tid >> 4;
    float acc[4] = {};
    #pragma unroll
    for (int k4 = 0; k4 < 16; k4++) {
        float b0 = Bs[4 * k4 + 0][tc];
        float b1 = Bs[4 * k4 + 1][tc];
        float b2 = Bs[4 * k4 + 2][tc];
        float b3 = Bs[4 * k4 + 3][tc];
        #pragma unroll
        for (int i = 0; i < 4; i++) {
            float4 av = *reinterpret_cast<const float4*>(&As[r0 + i * 16][4 * k4]);
            acc[i] += av.x * b0 + av.y * b1 + av.z * b2 + av.w * b3;
        }
    }
    #pragma unroll
    for (int i = 0; i < 4; i++) {
        int m = bm + r0 + i * 16;
        if (m < M) C[(size_t)m * 16 + tc] = acc[i];
    }
}

// ================= per-node attention scores =================
__global__ void scores_kernel(const float* __restrict__ h,
                              const float* __restrict__ asrc,
                              const float* __restrict__ adst,
                              float* __restrict__ es, float* __restrict__ ed,
                              int Nn, int H, int C) {
    int idx = blockIdx.x * blockDim.x + threadIdx.x;
    if (idx >= Nn * H) return;
    int n = idx / H, hh = idx % H;
    const float4* hp = reinterpret_cast<const float4*>(h + ((size_t)n * H + hh) * C);
    const float4* ap = reinterpret_cast<const float4*>(asrc + hh * C);
    const float4* bp = reinterpret_cast<const float4*>(adst + hh * C);
    float s = 0.f, d = 0.f;
    for (int c4 = 0; c4 < C / 4; c4++) {
        float4 v = hp[c4], a = ap[c4], b = bp[c4];
        s += v.x * a.x + v.y * a.y + v.z * a.z + v.w * a.w;
        d += v.x * b.x + v.y * b.y + v.z * b.z + v.w * b.w;
    }
    es[idx] = s;
    ed[idx] = d;
}

// ================= CSR build =================
__global__ void hist_kernel(const int* __restrict__ dst, int* __restrict__ counts,
                            int E0, int Etot) {
    int e = blockIdx.x * blockDim.x + threadIdx.x;
    if (e >= Etot) return;
    int d_ = (e < E0) ? dst[e] : e - E0;
    atomicAdd(&counts[d_], 1);
}

__global__ void scan_kernel(const int* __restrict__ counts, int* __restrict__ row_ptr, int Nn) {
    __shared__ int wsum[16];
    __shared__ int chunk_total;
    __shared__ int carry_s;
    const int tid = threadIdx.x;
    const int lane = tid & 63;
    const int wid = tid >> 6;
    if (tid == 0) carry_s = 0;
    __syncthreads();
    for (int base = 0; base < Nn; base += 1024) {
        int i = base + tid;
        int v = (i < Nn) ? counts[i] : 0;
        int iv = v;
        #pragma unroll
        for (int off = 1; off < 64; off <<= 1) {
            int t = __shfl_up(iv, off, 64);
            if (lane >= off) iv += t;
        }
        if (lane == 63) wsum[wid] = iv;
        __syncthreads();
        if (tid == 0) {
            int s = 0;
            #pragma unroll
            for (int k = 0; k < 16; k++) { int t = wsum[k]; wsum[k] = s; s += t; }
            chunk_total = s;
        }
        __syncthreads();
        if (i < Nn) row_ptr[i] = carry_s + wsum[wid] + (iv - v);
        __syncthreads();
        if (tid == 0) carry_s += chunk_total;
        __syncthreads();
    }
    if (tid == 0) row_ptr[Nn] = carry_s;
}

__global__ void scatter_kernel(const int* __restrict__ src, const int* __restrict__ dst,
                               int* __restrict__ cursor, int* __restrict__ col,
                               int E0, int Etot) {
    int e = blockIdx.x * blockDim.x + threadIdx.x;
    if (e >= Etot) return;
    int d_ = (e < E0) ? dst[e] : e - E0;
    int s_ = (e < E0) ? src[e] : e - E0;
    int pos = atomicAdd(&cursor[d_], 1);
    col[pos] = s_;
}

// ========== fused softmax (no max shift; shift-invariant) + aggregate + epilogue ==========
template<int H, int C, int NT, int DO_ELU>
__launch_bounds__(256)
__global__ void gat_fused(const int* __restrict__ row_ptr, const int* __restrict__ col,
                          const float* __restrict__ es, const float* __restrict__ ed,
                          const float* __restrict__ hbuf, float* __restrict__ out,
                          const float* __restrict__ bias, const float* __restrict__ g,
                          const float* __restrict__ be, const float* __restrict__ rm,
                          const float* __restrict__ rv, int Nn) {
    constexpr int Dout = H * C;
    constexpr int VEC = Dout / NT;
    constexpr int NPB = 256 / NT;        // nodes per block
    constexpr int CH = 64;               // edge chunk
    __shared__ float w_s[NPB][CH][H];
    __shared__ int   c_s[NPB][CH];
    __shared__ float ed_s[NPB][H];
    __shared__ int   md;
    const int tid = threadIdx.x;
    const int slot = tid / NT;
    const int t = tid % NT;
    const int node = blockIdx.x * NPB + slot;
    const bool alive = node < Nn;
    int jb = 0, je = 0;
    if (alive) { jb = row_ptr[node]; je = row_ptr[node + 1]; }
    if (tid == 0) md = 0;
    __syncthreads();
    if (alive && t == 0) atomicMax(&md, je - jb);
    if (alive && t < H) ed_s[slot][t] = ed[node * H + t];
    __syncthreads();
    const int nch = (md + CH - 1) / CH;
    const int c0 = t * VEC;
    const int hh = c0 / C;
    float acc[VEC] = {};
    float den = 0.f;
    for (int cc = 0; cc < nch; cc++) {
        int j0 = jb + cc * CH;
        int cnt = je - j0;
        if (cnt > CH) cnt = CH;
        if (alive) {
            // strided so ALL CH entries get filled even when NT < CH
            for (int tt = t; tt < cnt; tt += NT) {
                int s = col[j0 + tt];
                c_s[slot][tt] = s;
                if constexpr (H == 8) {
                    const float4* ep = reinterpret_cast<const float4*>(&es[s * 8]);
                    float4 e0 = ep[0], e1 = ep[1];
                    float al[8] = {e0.x, e0.y, e0.z, e0.w, e1.x, e1.y, e1.z, e1.w};
                    #pragma unroll
                    for (int h2 = 0; h2 < 8; h2++) {
                        float a = al[h2] + ed_s[slot][h2];
                        a = (a >= 0.f) ? a : NEG_SLOPE * a;
                        w_s[slot][tt][h2] = __expf(a);
                    }
                } else {
                    float a = es[s] + ed_s[slot][0];
                    a = (a >= 0.f) ? a : NEG_SLOPE * a;
                    w_s[slot][tt][0] = __expf(a);
                }
            }
        }
        __syncthreads();
        if (alive && cnt > 0) {
            for (int j = 0; j < cnt; j++) {
                float w = w_s[slot][j][hh];
                den += w;
                const float* hp = hbuf + (size_t)c_s[slot][j] * Dout + c0;
                if constexpr (VEC == 4) {
                    const float4 hv = *reinterpret_cast<const float4*>(hp);
                    acc[0] += w * hv.x; acc[1] += w * hv.y;
                    acc[2] += w * hv.z; acc[3] += w * hv.w;
                } else if constexpr (VEC == 2) {
                    const float2 hv = *reinterpret_cast<const float2*>(hp);
                    acc[0] += w * hv.x; acc[1] += w * hv.y;
                } else {
                    acc[0] += w * hp[0];
                }
            }
        }
        __syncthreads();
    }
    if (!alive) return;
    const float inv = 1.f / (den + 1e-16f);
    float res[VEC];
    #pragma unroll
    for (int v = 0; v < VEC; v++) {
        const int jc = c0 + v;
        float y = acc[v] * inv + bias[jc];
        if (DO_ELU) y = (y > 0.f) ? y : expm1f(y);
        y = (y - rm[jc]) * rsqrtf(rv[jc] + BN_EPS) * g[jc] + be[jc];
        res[v] = y;
    }
    float* op = out + (size_t)node * Dout + c0;
    if constexpr (VEC == 4) {
        *reinterpret_cast<float4*>(op) = make_float4(res[0], res[1], res[2], res[3]);
    } else if constexpr (VEC == 2) {
        *reinterpret_cast<float2*>(op) = make_float2(res[0], res[1]);
    } else {
        op[0] = res[0];
    }
}

extern "C" void kernel_launch(void* const* d_in, const int* in_sizes, int n_in,
                              void* d_out, int out_size, void* d_ws, size_t ws_size,
                              hipStream_t stream) {
    const float* x = (const float*)d_in[0];
    const int* src = (const int*)d_in[1];
    const int* dst = (const int*)d_in[2];
    const int Nn = in_sizes[0] / 128;   // 50000
    const int E0 = in_sizes[1];         // 400000
    const int Etot = E0 + Nn;

    // workspace layout
    float* B0 = (float*)d_ws;                       // N*256
    float* B1 = B0 + (size_t)Nn * 256;              // N*256
    float* es = B1 + (size_t)Nn * 256;              // N*8
    float* ed = es + (size_t)Nn * 8;                // N*8
    int* row_ptr = (int*)(ed + (size_t)Nn * 8);     // N+1
    int* cursor  = row_ptr + (Nn + 1);              // N
    int* col     = cursor + Nn;                     // Etot

    // ---- CSR build ----
    hipMemsetAsync(cursor, 0, sizeof(int) * Nn, stream);
    hist_kernel<<<(Etot + 255) / 256, 256, 0, stream>>>(dst, cursor, E0, Etot);
    scan_kernel<<<1, 1024, 0, stream>>>(cursor, row_ptr, Nn);
    hipMemcpyAsync(cursor, row_ptr, sizeof(int) * Nn, hipMemcpyDeviceToDevice, stream);
    scatter_kernel<<<(Etot + 255) / 256, 256, 0, stream>>>(src, dst, cursor, col, E0, Etot);

    const int   din_l[4] = {128, 256, 128, 64};
    const int   H_l[4]   = {8, 8, 8, 1};
    const int   C_l[4]   = {32, 16, 8, 16};
    const float* in_l[4] = { x, B1, B0 + (size_t)Nn * 128, B1 + (size_t)Nn * 64 };
    float* h_l[4]   = { B0, B0, B1, B0 };
    float* agg_l[4] = { B1, B0 + (size_t)Nn * 128, B1 + (size_t)Nn * 64, (float*)d_out };

    const int gy = (Nn + 127) / 128;

    for (int l = 0; l < 4; l++) {
        const int din = din_l[l], H = H_l[l], C = C_l[l];
        const float* const* p = (const float* const*)(d_in + 3 + l * 8);
        const float* W    = p[0];
        const float* asrc = p[1];
        const float* adst = p[2];
        const float* bias = p[3];
        const float* g    = p[4];
        const float* be   = p[5];
        const float* rm   = p[6];
        const float* rv   = p[7];
        const float* in = in_l[l];
        float* h   = h_l[l];
        float* agg = agg_l[l];

        // 1. h = in @ W
        if (l == 0) {
            gemm_tile<8><<<dim3(2, gy), 256, 0, stream>>>(in, W, h, Nn, din, 256);
        } else if (l == 1) {
            gemm_tile<8><<<dim3(1, gy), 256, 0, stream>>>(in, W, h, Nn, din, 128);
        } else if (l == 2) {
            gemm_tile<4><<<dim3(1, gy), 256, 0, stream>>>(in, W, h, Nn, din, 64);
        } else {
            gemm_k64n16<<<(Nn + 63) / 64, 256, 0, stream>>>(in, W, h, Nn);
        }

        // 2. per-node scores
        int t1 = Nn * H;
        scores_kernel<<<(t1 + 255) / 256, 256, 0, stream>>>(h, asrc, adst, es, ed, Nn, H, C);

        // 3. fused softmax + aggregate + epilogue
        if (l == 0) {
            gat_fused<8, 32, 64, 1><<<(Nn + 3) / 4, 256, 0, stream>>>(
                row_ptr, col, es, ed, h, agg, bias, g, be, rm, rv, Nn);
        } else if (l == 1) {
            gat_fused<8, 16, 64, 1><<<(Nn + 3) / 4, 256, 0, stream>>>(
                row_ptr, col, es, ed, h, agg, bias, g, be, rm, rv, Nn);
        } else if (l == 2) {
            gat_fused<8, 8, 64, 1><<<(Nn + 3) / 4, 256, 0, stream>>>(
                row_ptr, col, es, ed, h, agg, bias, g, be, rm, rv, Nn);
        } else {
            gat_fused<1, 16, 16, 0><<<(Nn + 15) / 16, 256, 0, stream>>>(
                row_ptr, col, es, ed, h, agg, bias, g, be, rm, rv, Nn);
        }
    }
}

// Round 5
// 441.842 us; speedup vs baseline: 3.0225x; 1.0916x over previous
//
#include <hip/hip_runtime.h>

#define NEG_SLOPE 0.2f
#define BN_EPS 1e-5f

typedef unsigned short u16;
typedef unsigned int u32;
typedef __bf16 bf16x8 __attribute__((ext_vector_type(8)));
typedef float f32x4 __attribute__((ext_vector_type(4)));

__device__ __forceinline__ u32 f2bf(float f) {
    u32 u = __float_as_uint(f);
    return (u + 0x7FFFu + ((u >> 16) & 1u)) >> 16;
}
__device__ __forceinline__ float bf2f(u32 h) { return __uint_as_float(h << 16); }

// ========== split fp32 -> (hi, lo) bf16 pair, 4 elems/thread ==========
__global__ void split_kernel(const float4* __restrict__ X, uint2* __restrict__ hi,
                             uint2* __restrict__ lo, int n4) {
    int i = blockIdx.x * blockDim.x + threadIdx.x;
    if (i >= n4) return;
    float4 v = X[i];
    u32 h0 = f2bf(v.x), h1 = f2bf(v.y), h2 = f2bf(v.z), h3 = f2bf(v.w);
    hi[i] = make_uint2(h0 | (h1 << 16), h2 | (h3 << 16));
    u32 l0 = f2bf(v.x - bf2f(h0)), l1 = f2bf(v.y - bf2f(h1)),
        l2 = f2bf(v.z - bf2f(h2)), l3 = f2bf(v.w - bf2f(h3));
    lo[i] = make_uint2(l0 | (l1 << 16), l2 | (l3 << 16));
}

// ========== weight prep: W[K][N] fp32 -> Wt hi/lo bf16 [N][K] ==========
__global__ void wt_prep(const float* __restrict__ W, u16* __restrict__ hi,
                        u16* __restrict__ lo, int K, int N) {
    int i = blockIdx.x * blockDim.x + threadIdx.x;
    if (i >= K * N) return;
    int k = i / N, n = i - k * N;
    float w = W[i];
    u32 h = f2bf(w);
    hi[n * K + k] = (u16)h;
    lo[n * K + k] = (u16)f2bf(w - bf2f(h));
}

// ========== split-bf16 MFMA GEMM: C[M][N] = A[M][K] @ B[K][N] ==========
// A given as Ahi/Alo bf16 [M][K]; B given as Bhi/Blo bf16 [N][K] (transposed).
// 128x128 tile, 4 waves (2x2 of 64x64), 16x16x32 MFMA, 3 products (hh, hl, lh).
__launch_bounds__(256)
__global__ void gemm_mfma(const u16* __restrict__ Ahi, const u16* __restrict__ Alo,
                          const u16* __restrict__ Bhi, const u16* __restrict__ Blo,
                          float* __restrict__ C, int M, int K, int N) {
    __shared__ uint4 sA[2][512];     // [hi/lo][row*4 + swizzled slot], row=0..127
    __shared__ uint4 sB[2][512];
    const int tid = threadIdx.x;
    const int bm = blockIdx.y * 128;
    const int bn = blockIdx.x * 128;
    const int lane = tid & 63;
    const int w = tid >> 6;
    const int wm = (w >> 1) * 64;
    const int wn = (w & 1) * 64;
    const int fr = lane & 15;        // fragment row/col within 16
    const int fs = lane >> 4;        // k-slot 0..3
    f32x4 zero = {0.f, 0.f, 0.f, 0.f};
    f32x4 acc[4][4];
    #pragma unroll
    for (int i = 0; i < 4; i++)
        #pragma unroll
        for (int j = 0; j < 4; j++) acc[i][j] = zero;

    const int r0 = tid >> 2;         // staging rows: r0 in 0..63, r1 in 64..127
    const int ss = tid & 3;
    const int r1 = r0 + 64;
    const int d0 = r0 * 4 + (ss ^ ((r0 >> 1) & 3));
    const int d1 = r1 * 4 + (ss ^ ((r1 >> 1) & 3));

    for (int k0 = 0; k0 < K; k0 += 32) {
        // --- stage A tiles (guard M) ---
        {
            int gr = bm + r0;
            uint4 vh = make_uint4(0, 0, 0, 0), vl = make_uint4(0, 0, 0, 0);
            if (gr < M) {
                vh = *(const uint4*)(Ahi + (size_t)gr * K + k0 + ss * 8);
                vl = *(const uint4*)(Alo + (size_t)gr * K + k0 + ss * 8);
            }
            sA[0][d0] = vh; sA[1][d0] = vl;
            gr = bm + r1;
            vh = make_uint4(0, 0, 0, 0); vl = make_uint4(0, 0, 0, 0);
            if (gr < M) {
                vh = *(const uint4*)(Ahi + (size_t)gr * K + k0 + ss * 8);
                vl = *(const uint4*)(Alo + (size_t)gr * K + k0 + ss * 8);
            }
            sA[0][d1] = vh; sA[1][d1] = vl;
        }
        // --- stage B tiles (N multiple of 128, no guard) ---
        {
            int gr = bn + r0;
            sB[0][d0] = *(const uint4*)(Bhi + (size_t)gr * K + k0 + ss * 8);
            sB[1][d0] = *(const uint4*)(Blo + (size_t)gr * K + k0 + ss * 8);
            gr = bn + r1;
            sB[0][d1] = *(const uint4*)(Bhi + (size_t)gr * K + k0 + ss * 8);
            sB[1][d1] = *(const uint4*)(Blo + (size_t)gr * K + k0 + ss * 8);
        }
        __syncthreads();
        bf16x8 ah[4], al[4], bh[4], bl[4];
        #pragma unroll
        for (int mi = 0; mi < 4; mi++) {
            int row = wm + mi * 16 + fr;
            int idx = row * 4 + (fs ^ ((row >> 1) & 3));
            ah[mi] = *reinterpret_cast<const bf16x8*>(&sA[0][idx]);
            al[mi] = *reinterpret_cast<const bf16x8*>(&sA[1][idx]);
        }
        #pragma unroll
        for (int ni = 0; ni < 4; ni++) {
            int row = wn + ni * 16 + fr;
            int idx = row * 4 + (fs ^ ((row >> 1) & 3));
            bh[ni] = *reinterpret_cast<const bf16x8*>(&sB[0][idx]);
            bl[ni] = *reinterpret_cast<const bf16x8*>(&sB[1][idx]);
        }
        #pragma unroll
        for (int mi = 0; mi < 4; mi++)
            #pragma unroll
            for (int ni = 0; ni < 4; ni++) {
                acc[mi][ni] = __builtin_amdgcn_mfma_f32_16x16x32_bf16(ah[mi], bh[ni], acc[mi][ni], 0, 0, 0);
                acc[mi][ni] = __builtin_amdgcn_mfma_f32_16x16x32_bf16(ah[mi], bl[ni], acc[mi][ni], 0, 0, 0);
                acc[mi][ni] = __builtin_amdgcn_mfma_f32_16x16x32_bf16(al[mi], bh[ni], acc[mi][ni], 0, 0, 0);
            }
        __syncthreads();
    }
    // C/D layout (verified m89): col = lane&15, row = (lane>>4)*4 + reg
    #pragma unroll
    for (int mi = 0; mi < 4; mi++) {
        #pragma unroll
        for (int ni = 0; ni < 4; ni++) {
            int colg = bn + wn + ni * 16 + fr;
            int rbase = bm + wm + mi * 16 + fs * 4;
            #pragma unroll
            for (int r = 0; r < 4; r++) {
                int rw = rbase + r;
                if (rw < M) C[(size_t)rw * N + colg] = acc[mi][ni][r];
            }
        }
    }
}

// ================= fp32 GEMM for layer 3 (K=128, N=64) =================
template<int TN>
__launch_bounds__(256)
__global__ void gemm_tile(const float* __restrict__ A, const float* __restrict__ B,
                          float* __restrict__ C, int M, int K, int N) {
    constexpr int BNt = 16 * TN;
    __shared__ float As[32][132];
    __shared__ float Bs[32][BNt + 4];
    const int bm = blockIdx.y * 128;
    const int bn = blockIdx.x * BNt;
    const int tid = threadIdx.x;
    const int tr = tid >> 4;
    const int tc = tid & 15;
    const int la_m = tid >> 3;
    const int la_k = (tid & 7) << 2;
    const int lb_row = tid / (BNt / 4);
    const int lb_c = (tid % (BNt / 4)) * 4;
    float acc[8][TN] = {};
    for (int k0 = 0; k0 < K; k0 += 32) {
        #pragma unroll
        for (int p = 0; p < 4; p++) {
            int m = la_m + p * 32;
            int gm = bm + m;
            float4 v = make_float4(0.f, 0.f, 0.f, 0.f);
            if (gm < M) v = *reinterpret_cast<const float4*>(&A[(size_t)gm * K + k0 + la_k]);
            As[la_k + 0][m] = v.x;
            As[la_k + 1][m] = v.y;
            As[la_k + 2][m] = v.z;
            As[la_k + 3][m] = v.w;
        }
        #pragma unroll
        for (int p = 0; p < BNt / 32; p++) {
            int kk = lb_row + p * (1024 / BNt);
            *reinterpret_cast<float4*>(&Bs[kk][lb_c]) =
                *reinterpret_cast<const float4*>(&B[(size_t)(k0 + kk) * N + bn + lb_c]);
        }
        __syncthreads();
        #pragma unroll
        for (int kk = 0; kk < 32; kk++) {
            float a[8], b[TN];
            float4 a0 = *reinterpret_cast<const float4*>(&As[kk][tr * 4]);
            float4 a1 = *reinterpret_cast<const float4*>(&As[kk][64 + tr * 4]);
            a[0] = a0.x; a[1] = a0.y; a[2] = a0.z; a[3] = a0.w;
            a[4] = a1.x; a[5] = a1.y; a[6] = a1.z; a[7] = a1.w;
            float4 b0 = *reinterpret_cast<const float4*>(&Bs[kk][tc * 4]);
            b[0] = b0.x; b[1] = b0.y; b[2] = b0.z; b[3] = b0.w;
            if constexpr (TN == 8) {
                float4 b1 = *reinterpret_cast<const float4*>(&Bs[kk][64 + tc * 4]);
                b[4] = b1.x; b[5] = b1.y; b[6] = b1.z; b[7] = b1.w;
            }
            #pragma unroll
            for (int i = 0; i < 8; i++)
                #pragma unroll
                for (int j = 0; j < TN; j++)
                    acc[i][j] += a[i] * b[j];
        }
        __syncthreads();
    }
    #pragma unroll
    for (int i = 0; i < 8; i++) {
        int m = bm + ((i < 4) ? (tr * 4 + i) : (64 + tr * 4 + (i - 4)));
        if (m >= M) continue;
        float4 v0 = make_float4(acc[i][0], acc[i][1], acc[i][2], acc[i][3]);
        *reinterpret_cast<float4*>(&C[(size_t)m * N + bn + tc * 4]) = v0;
        if constexpr (TN == 8) {
            float4 v1 = make_float4(acc[i][4], acc[i][5], acc[i][6], acc[i][7]);
            *reinterpret_cast<float4*>(&C[(size_t)m * N + bn + 64 + tc * 4]) = v1;
        }
    }
}

// ================= small GEMM for layer 4: K=64, N=16 =================
__launch_bounds__(256)
__global__ void gemm_k64n16(const float* __restrict__ A, const float* __restrict__ B,
                            float* __restrict__ C, int M) {
    __shared__ float As[64][68];
    __shared__ float Bs[64][16];
    const int tid = threadIdx.x;
    const int bm = blockIdx.x * 64;
    {
        int r = tid >> 2, c = (tid & 3) << 2;
        *reinterpret_cast<float4*>(&Bs[r][c]) = *reinterpret_cast<const float4*>(&B[r * 16 + c]);
    }
    #pragma unroll
    for (int p = 0; p < 4; p++) {
        int m = (tid >> 4) + p * 16;
        int c = (tid & 15) << 2;
        int gm = bm + m;
        float4 v = make_float4(0.f, 0.f, 0.f, 0.f);
        if (gm < M) v = *reinterpret_cast<const float4*>(&A[(size_t)gm * 64 + c]);
        *reinterpret_cast<float4*>(&As[m][c]) = v;
    }
    __syncthreads();
    const int tc = tid & 15;
    const int r0 = tid >> 4;
    float acc[4] = {};
    #pragma unroll
    for (int k4 = 0; k4 < 16; k4++) {
        float b0 = Bs[4 * k4 + 0][tc];
        float b1 = Bs[4 * k4 + 1][tc];
        float b2 = Bs[4 * k4 + 2][tc];
        float b3 = Bs[4 * k4 + 3][tc];
        #pragma unroll
        for (int i = 0; i < 4; i++) {
            float4 av = *reinterpret_cast<const float4*>(&As[r0 + i * 16][4 * k4]);
            acc[i] += av.x * b0 + av.y * b1 + av.z * b2 + av.w * b3;
        }
    }
    #pragma unroll
    for (int i = 0; i < 4; i++) {
        int m = bm + r0 + i * 16;
        if (m < M) C[(size_t)m * 16 + tc] = acc[i];
    }
}

// ================= per-node attention scores =================
__global__ void scores_kernel(const float* __restrict__ h,
                              const float* __restrict__ asrc,
                              const float* __restrict__ adst,
                              float* __restrict__ es, float* __restrict__ ed,
                              int Nn, int H, int C) {
    int idx = blockIdx.x * blockDim.x + threadIdx.x;
    if (idx >= Nn * H) return;
    int n = idx / H, hh = idx % H;
    const float4* hp = reinterpret_cast<const float4*>(h + ((size_t)n * H + hh) * C);
    const float4* ap = reinterpret_cast<const float4*>(asrc + hh * C);
    const float4* bp = reinterpret_cast<const float4*>(adst + hh * C);
    float s = 0.f, d = 0.f;
    for (int c4 = 0; c4 < C / 4; c4++) {
        float4 v = hp[c4], a = ap[c4], b = bp[c4];
        s += v.x * a.x + v.y * a.y + v.z * a.z + v.w * a.w;
        d += v.x * b.x + v.y * b.y + v.z * b.z + v.w * b.w;
    }
    es[idx] = s;
    ed[idx] = d;
}

// ================= CSR build =================
__global__ void hist_kernel(const int* __restrict__ dst, int* __restrict__ counts,
                            int E0, int Etot) {
    int e = blockIdx.x * blockDim.x + threadIdx.x;
    if (e >= Etot) return;
    int d_ = (e < E0) ? dst[e] : e - E0;
    atomicAdd(&counts[d_], 1);
}

__global__ void scan_kernel(const int* __restrict__ counts, int* __restrict__ row_ptr, int Nn) {
    __shared__ int wsum[16];
    __shared__ int chunk_total;
    __shared__ int carry_s;
    const int tid = threadIdx.x;
    const int lane = tid & 63;
    const int wid = tid >> 6;
    if (tid == 0) carry_s = 0;
    __syncthreads();
    for (int base = 0; base < Nn; base += 1024) {
        int i = base + tid;
        int v = (i < Nn) ? counts[i] : 0;
        int iv = v;
        #pragma unroll
        for (int off = 1; off < 64; off <<= 1) {
            int t = __shfl_up(iv, off, 64);
            if (lane >= off) iv += t;
        }
        if (lane == 63) wsum[wid] = iv;
        __syncthreads();
        if (tid == 0) {
            int s = 0;
            #pragma unroll
            for (int k = 0; k < 16; k++) { int t = wsum[k]; wsum[k] = s; s += t; }
            chunk_total = s;
        }
        __syncthreads();
        if (i < Nn) row_ptr[i] = carry_s + wsum[wid] + (iv - v);
        __syncthreads();
        if (tid == 0) carry_s += chunk_total;
        __syncthreads();
    }
    if (tid == 0) row_ptr[Nn] = carry_s;
}

__global__ void scatter_kernel(const int* __restrict__ src, const int* __restrict__ dst,
                               int* __restrict__ cursor, int* __restrict__ col,
                               int E0, int Etot) {
    int e = blockIdx.x * blockDim.x + threadIdx.x;
    if (e >= Etot) return;
    int d_ = (e < E0) ? dst[e] : e - E0;
    int s_ = (e < E0) ? src[e] : e - E0;
    int pos = atomicAdd(&cursor[d_], 1);
    col[pos] = s_;
}

// ========== fused softmax + aggregate + bias + ELU + BN, 4-deep gather pipeline ==========
template<int H, int C, int NT, int DO_ELU>
__launch_bounds__(256)
__global__ void gat_fused(const int* __restrict__ row_ptr, const int* __restrict__ col,
                          const float* __restrict__ es, const float* __restrict__ ed,
                          const float* __restrict__ hbuf, float* __restrict__ out,
                          const float* __restrict__ bias, const float* __restrict__ g,
                          const float* __restrict__ be, const float* __restrict__ rm,
                          const float* __restrict__ rv, int Nn) {
    constexpr int Dout = H * C;
    constexpr int VEC = Dout / NT;
    constexpr int NPB = 256 / NT;
    constexpr int CH = 64;
    __shared__ float w_s[NPB][CH][H];
    __shared__ int   c_s[NPB][CH];
    __shared__ float ed_s[NPB][H];
    __shared__ int   md;
    const int tid = threadIdx.x;
    const int slot = tid / NT;
    const int t = tid % NT;
    const int node = blockIdx.x * NPB + slot;
    const bool alive = node < Nn;
    int jb = 0, je = 0;
    if (alive) { jb = row_ptr[node]; je = row_ptr[node + 1]; }
    if (tid == 0) md = 0;
    __syncthreads();
    if (alive && t == 0) atomicMax(&md, je - jb);
    if (alive && t < H) ed_s[slot][t] = ed[node * H + t];
    __syncthreads();
    const int nch = (md + CH - 1) / CH;
    const int c0 = t * VEC;
    const int hh = c0 / C;
    float acc[VEC] = {};
    float den = 0.f;
    for (int cc = 0; cc < nch; cc++) {
        int j0 = jb + cc * CH;
        int cnt = je - j0;
        if (cnt > CH) cnt = CH;
        if (alive) {
            for (int tt = t; tt < cnt; tt += NT) {
                int s = col[j0 + tt];
                c_s[slot][tt] = s;
                if constexpr (H == 8) {
                    const float4* ep = reinterpret_cast<const float4*>(&es[s * 8]);
                    float4 e0 = ep[0], e1 = ep[1];
                    float al[8] = {e0.x, e0.y, e0.z, e0.w, e1.x, e1.y, e1.z, e1.w};
                    #pragma unroll
                    for (int h2 = 0; h2 < 8; h2++) {
                        float a = al[h2] + ed_s[slot][h2];
                        a = (a >= 0.f) ? a : NEG_SLOPE * a;
                        w_s[slot][tt][h2] = __expf(a);
                    }
                } else {
                    float a = es[s] + ed_s[slot][0];
                    a = (a >= 0.f) ? a : NEG_SLOPE * a;
                    w_s[slot][tt][0] = __expf(a);
                }
            }
        }
        __syncthreads();
        if (alive && cnt > 0) {
            int j = 0;
            if constexpr (VEC == 4) {
                for (; j + 4 <= cnt; j += 4) {
                    int s0 = c_s[slot][j],     s1 = c_s[slot][j + 1];
                    int s2 = c_s[slot][j + 2], s3 = c_s[slot][j + 3];
                    float w0 = w_s[slot][j][hh],     w1 = w_s[slot][j + 1][hh];
                    float w2 = w_s[slot][j + 2][hh], w3 = w_s[slot][j + 3][hh];
                    const float4 v0 = *reinterpret_cast<const float4*>(hbuf + (size_t)s0 * Dout + c0);
                    const float4 v1 = *reinterpret_cast<const float4*>(hbuf + (size_t)s1 * Dout + c0);
                    const float4 v2 = *reinterpret_cast<const float4*>(hbuf + (size_t)s2 * Dout + c0);
                    const float4 v3 = *reinterpret_cast<const float4*>(hbuf + (size_t)s3 * Dout + c0);
                    den += (w0 + w1) + (w2 + w3);
                    acc[0] += w0 * v0.x + w1 * v1.x + w2 * v2.x + w3 * v3.x;
                    acc[1] += w0 * v0.y + w1 * v1.y + w2 * v2.y + w3 * v3.y;
                    acc[2] += w0 * v0.z + w1 * v1.z + w2 * v2.z + w3 * v3.z;
                    acc[3] += w0 * v0.w + w1 * v1.w + w2 * v2.w + w3 * v3.w;
                }
            } else if constexpr (VEC == 2) {
                for (; j + 4 <= cnt; j += 4) {
                    int s0 = c_s[slot][j],     s1 = c_s[slot][j + 1];
                    int s2 = c_s[slot][j + 2], s3 = c_s[slot][j + 3];
                    float w0 = w_s[slot][j][hh],     w1 = w_s[slot][j + 1][hh];
                    float w2 = w_s[slot][j + 2][hh], w3 = w_s[slot][j + 3][hh];
                    const float2 v0 = *reinterpret_cast<const float2*>(hbuf + (size_t)s0 * Dout + c0);
                    const float2 v1 = *reinterpret_cast<const float2*>(hbuf + (size_t)s1 * Dout + c0);
                    const float2 v2 = *reinterpret_cast<const float2*>(hbuf + (size_t)s2 * Dout + c0);
                    const float2 v3 = *reinterpret_cast<const float2*>(hbuf + (size_t)s3 * Dout + c0);
                    den += (w0 + w1) + (w2 + w3);
                    acc[0] += w0 * v0.x + w1 * v1.x + w2 * v2.x + w3 * v3.x;
                    acc[1] += w0 * v0.y + w1 * v1.y + w2 * v2.y + w3 * v3.y;
                }
            } else {
                for (; j + 4 <= cnt; j += 4) {
                    int s0 = c_s[slot][j],     s1 = c_s[slot][j + 1];
                    int s2 = c_s[slot][j + 2], s3 = c_s[slot][j + 3];
                    float w0 = w_s[slot][j][hh],     w1 = w_s[slot][j + 1][hh];
                    float w2 = w_s[slot][j + 2][hh], w3 = w_s[slot][j + 3][hh];
                    float v0 = hbuf[(size_t)s0 * Dout + c0];
                    float v1 = hbuf[(size_t)s1 * Dout + c0];
                    float v2 = hbuf[(size_t)s2 * Dout + c0];
                    float v3 = hbuf[(size_t)s3 * Dout + c0];
                    den += (w0 + w1) + (w2 + w3);
                    acc[0] += w0 * v0 + w1 * v1 + w2 * v2 + w3 * v3;
                }
            }
            for (; j < cnt; j++) {
                float w = w_s[slot][j][hh];
                den += w;
                const float* hp = hbuf + (size_t)c_s[slot][j] * Dout + c0;
                if constexpr (VEC == 4) {
                    const float4 hv = *reinterpret_cast<const float4*>(hp);
                    acc[0] += w * hv.x; acc[1] += w * hv.y;
                    acc[2] += w * hv.z; acc[3] += w * hv.w;
                } else if constexpr (VEC == 2) {
                    const float2 hv = *reinterpret_cast<const float2*>(hp);
                    acc[0] += w * hv.x; acc[1] += w * hv.y;
                } else {
                    acc[0] += w * hp[0];
                }
            }
        }
        __syncthreads();
    }
    if (!alive) return;
    const float inv = 1.f / (den + 1e-16f);
    float res[VEC];
    #pragma unroll
    for (int v = 0; v < VEC; v++) {
        const int jc = c0 + v;
        float y = acc[v] * inv + bias[jc];
        if (DO_ELU) y = (y > 0.f) ? y : expm1f(y);
        y = (y - rm[jc]) * rsqrtf(rv[jc] + BN_EPS) * g[jc] + be[jc];
        res[v] = y;
    }
    float* op = out + (size_t)node * Dout + c0;
    if constexpr (VEC == 4) {
        *reinterpret_cast<float4*>(op) = make_float4(res[0], res[1], res[2], res[3]);
    } else if constexpr (VEC == 2) {
        *reinterpret_cast<float2*>(op) = make_float2(res[0], res[1]);
    } else {
        op[0] = res[0];
    }
}

extern "C" void kernel_launch(void* const* d_in, const int* in_sizes, int n_in,
                              void* d_out, int out_size, void* d_ws, size_t ws_size,
                              hipStream_t stream) {
    const float* x = (const float*)d_in[0];
    const int* src = (const int*)d_in[1];
    const int* dst = (const int*)d_in[2];
    const int Nn = in_sizes[0] / 128;   // 50000
    const int E0 = in_sizes[1];         // 400000
    const int Etot = E0 + Nn;

    // workspace layout (unchanged footprint ~109 MB)
    float* B0 = (float*)d_ws;                       // Nn*256 f32
    float* B1 = B0 + (size_t)Nn * 256;              // Nn*256 f32
    float* es = B1 + (size_t)Nn * 256;              // Nn*8
    float* ed = es + (size_t)Nn * 8;                // Nn*8
    int* row_ptr = (int*)(ed + (size_t)Nn * 8);     // Nn+1
    int* cursor  = row_ptr + (Nn + 1);              // Nn
    int* col     = cursor + Nn;                     // Etot
    u16* wth = (u16*)(col + Etot);                  // 256*256
    u16* wtl = wth + 256 * 256;                     // 256*256

    // ---- CSR build ----
    hipMemsetAsync(cursor, 0, sizeof(int) * Nn, stream);
    hist_kernel<<<(Etot + 255) / 256, 256, 0, stream>>>(dst, cursor, E0, Etot);
    scan_kernel<<<1, 1024, 0, stream>>>(cursor, row_ptr, Nn);
    hipMemcpyAsync(cursor, row_ptr, sizeof(int) * Nn, hipMemcpyDeviceToDevice, stream);
    scatter_kernel<<<(Etot + 255) / 256, 256, 0, stream>>>(src, dst, cursor, col, E0, Etot);

    const int gy128 = (Nn + 127) / 128;

    for (int l = 0; l < 4; l++) {
        const float* const* p = (const float* const*)(d_in + 3 + l * 8);
        const float* W    = p[0];
        const float* asrc = p[1];
        const float* adst = p[2];
        const float* bias = p[3];
        const float* g    = p[4];
        const float* be   = p[5];
        const float* rm   = p[6];
        const float* rv   = p[7];

        if (l == 0) {
            // split x (Nn x 128) into B1 space; weights -> wth/wtl [256][128]
            const int K = 128, N = 256;
            u16* SH = (u16*)B1;
            u16* SL = SH + (size_t)Nn * K;
            int n4 = Nn * K / 4;
            split_kernel<<<(n4 + 255) / 256, 256, 0, stream>>>(
                (const float4*)x, (uint2*)SH, (uint2*)SL, n4);
            wt_prep<<<(K * N + 255) / 256, 256, 0, stream>>>(W, wth, wtl, K, N);
            float* h1 = B0;  // Nn x 256
            gemm_mfma<<<dim3(N / 128, gy128), 256, 0, stream>>>(SH, SL, wth, wtl, h1, Nn, K, N);
            scores_kernel<<<(Nn * 8 + 255) / 256, 256, 0, stream>>>(h1, asrc, adst, es, ed, Nn, 8, 32);
            gat_fused<8, 32, 64, 1><<<(Nn + 3) / 4, 256, 0, stream>>>(
                row_ptr, col, es, ed, h1, B1, bias, g, be, rm, rv, Nn);   // out1 -> B1
        } else if (l == 1) {
            // split out1 (B1, Nn x 256) into B0 space
            const int K = 256, N = 128;
            u16* SH = (u16*)B0;
            u16* SL = SH + (size_t)Nn * K;
            int n4 = Nn * K / 4;
            split_kernel<<<(n4 + 255) / 256, 256, 0, stream>>>(
                (const float4*)B1, (uint2*)SH, (uint2*)SL, n4);
            wt_prep<<<(K * N + 255) / 256, 256, 0, stream>>>(W, wth, wtl, K, N);
            float* h2 = B1;                       // Nn x 128 (first half of B1)
            float* out2 = B1 + (size_t)Nn * 128;  // Nn x 128 (second half)
            gemm_mfma<<<dim3(N / 128, gy128), 256, 0, stream>>>(SH, SL, wth, wtl, h2, Nn, K, N);
            scores_kernel<<<(Nn * 8 + 255) / 256, 256, 0, stream>>>(h2, asrc, adst, es, ed, Nn, 8, 16);
            gat_fused<8, 16, 64, 1><<<(Nn + 3) / 4, 256, 0, stream>>>(
                row_ptr, col, es, ed, h2, out2, bias, g, be, rm, rv, Nn);
        } else if (l == 2) {
            const float* in = B1 + (size_t)Nn * 128;  // out2
            float* h3 = B0;                            // Nn x 64
            float* out3 = B0 + (size_t)Nn * 64;        // Nn x 64
            gemm_tile<4><<<dim3(1, gy128), 256, 0, stream>>>(in, W, h3, Nn, 128, 64);
            scores_kernel<<<(Nn * 8 + 255) / 256, 256, 0, stream>>>(h3, asrc, adst, es, ed, Nn, 8, 8);
            gat_fused<8, 8, 64, 1><<<(Nn + 3) / 4, 256, 0, stream>>>(
                row_ptr, col, es, ed, h3, out3, bias, g, be, rm, rv, Nn);
        } else {
            const float* in = B0 + (size_t)Nn * 64;   // out3
            float* h4 = B1;                            // Nn x 16
            gemm_k64n16<<<(Nn + 63) / 64, 256, 0, stream>>>(in, W, h4, Nn);
            scores_kernel<<<(Nn + 255) / 256, 256, 0, stream>>>(h4, asrc, adst, es, ed, Nn, 1, 16);
            gat_fused<1, 16, 16, 0><<<(Nn + 15) / 16, 256, 0, stream>>>(
                row_ptr, col, es, ed, h4, (float*)d_out, bias, g, be, rm, rv, Nn);
        }
    }
}

// Round 6
// 407.148 us; speedup vs baseline: 3.2800x; 1.0852x over previous
//
#include <hip/hip_runtime.h>

#define NEG_SLOPE 0.2f
#define BN_EPS 1e-5f

typedef unsigned short u16;
typedef unsigned int u32;
typedef __bf16 bf16x8 __attribute__((ext_vector_type(8)));
typedef float f32x4 __attribute__((ext_vector_type(4)));

__device__ __forceinline__ u32 f2bf(float f) {
    u32 u = __float_as_uint(f);
    return (u + 0x7FFFu + ((u >> 16) & 1u)) >> 16;
}
__device__ __forceinline__ float bf2f(u32 h) { return __uint_as_float(h << 16); }
__device__ __forceinline__ float bfl(u32 p) { return __uint_as_float(p << 16); }
__device__ __forceinline__ float bfh(u32 p) { return __uint_as_float(p & 0xFFFF0000u); }

// ========== split fp32 -> (hi, lo) bf16 pair, 4 elems/thread ==========
__global__ void split_kernel(const float4* __restrict__ X, uint2* __restrict__ hi,
                             uint2* __restrict__ lo, int n4) {
    int i = blockIdx.x * blockDim.x + threadIdx.x;
    if (i >= n4) return;
    float4 v = X[i];
    u32 h0 = f2bf(v.x), h1 = f2bf(v.y), h2 = f2bf(v.z), h3 = f2bf(v.w);
    hi[i] = make_uint2(h0 | (h1 << 16), h2 | (h3 << 16));
    u32 l0 = f2bf(v.x - bf2f(h0)), l1 = f2bf(v.y - bf2f(h1)),
        l2 = f2bf(v.z - bf2f(h2)), l3 = f2bf(v.w - bf2f(h3));
    lo[i] = make_uint2(l0 | (l1 << 16), l2 | (l3 << 16));
}

// ========== weight prep: W[K][N] fp32 -> Wt hi/lo bf16 [N][K] ==========
__global__ void wt_prep(const float* __restrict__ W, u16* __restrict__ hi,
                        u16* __restrict__ lo, int K, int N) {
    int i = blockIdx.x * blockDim.x + threadIdx.x;
    if (i >= K * N) return;
    int k = i / N, n = i - k * N;
    float w = W[i];
    u32 h = f2bf(w);
    hi[n * K + k] = (u16)h;
    lo[n * K + k] = (u16)f2bf(w - bf2f(h));
}

// ========== split-bf16 MFMA GEMM -> bf16 output ==========
// A as Ahi/Alo bf16 [M][K]; B as Bhi/Blo bf16 [N][K] (transposed).
// 128x128 tile, 4 waves, 16x16x32 MFMA, 3 products (hh, hl, lh). C written as bf16.
__launch_bounds__(256)
__global__ void gemm_mfma(const u16* __restrict__ Ahi, const u16* __restrict__ Alo,
                          const u16* __restrict__ Bhi, const u16* __restrict__ Blo,
                          u16* __restrict__ Cbf, int M, int K, int N) {
    __shared__ uint4 sA[2][512];
    __shared__ uint4 sB[2][512];
    const int tid = threadIdx.x;
    const int bm = blockIdx.y * 128;
    const int bn = blockIdx.x * 128;
    const int lane = tid & 63;
    const int w = tid >> 6;
    const int wm = (w >> 1) * 64;
    const int wn = (w & 1) * 64;
    const int fr = lane & 15;
    const int fs = lane >> 4;
    f32x4 zero = {0.f, 0.f, 0.f, 0.f};
    f32x4 acc[4][4];
    #pragma unroll
    for (int i = 0; i < 4; i++)
        #pragma unroll
        for (int j = 0; j < 4; j++) acc[i][j] = zero;

    const int r0 = tid >> 2;
    const int ss = tid & 3;
    const int r1 = r0 + 64;
    const int d0 = r0 * 4 + (ss ^ ((r0 >> 1) & 3));
    const int d1 = r1 * 4 + (ss ^ ((r1 >> 1) & 3));

    for (int k0 = 0; k0 < K; k0 += 32) {
        {
            int gr = bm + r0;
            uint4 vh = make_uint4(0, 0, 0, 0), vl = make_uint4(0, 0, 0, 0);
            if (gr < M) {
                vh = *(const uint4*)(Ahi + (size_t)gr * K + k0 + ss * 8);
                vl = *(const uint4*)(Alo + (size_t)gr * K + k0 + ss * 8);
            }
            sA[0][d0] = vh; sA[1][d0] = vl;
            gr = bm + r1;
            vh = make_uint4(0, 0, 0, 0); vl = make_uint4(0, 0, 0, 0);
            if (gr < M) {
                vh = *(const uint4*)(Ahi + (size_t)gr * K + k0 + ss * 8);
                vl = *(const uint4*)(Alo + (size_t)gr * K + k0 + ss * 8);
            }
            sA[0][d1] = vh; sA[1][d1] = vl;
        }
        {
            int gr = bn + r0;
            sB[0][d0] = *(const uint4*)(Bhi + (size_t)gr * K + k0 + ss * 8);
            sB[1][d0] = *(const uint4*)(Blo + (size_t)gr * K + k0 + ss * 8);
            gr = bn + r1;
            sB[0][d1] = *(const uint4*)(Bhi + (size_t)gr * K + k0 + ss * 8);
            sB[1][d1] = *(const uint4*)(Blo + (size_t)gr * K + k0 + ss * 8);
        }
        __syncthreads();
        bf16x8 ah[4], al[4], bh[4], bl[4];
        #pragma unroll
        for (int mi = 0; mi < 4; mi++) {
            int row = wm + mi * 16 + fr;
            int idx = row * 4 + (fs ^ ((row >> 1) & 3));
            ah[mi] = *reinterpret_cast<const bf16x8*>(&sA[0][idx]);
            al[mi] = *reinterpret_cast<const bf16x8*>(&sA[1][idx]);
        }
        #pragma unroll
        for (int ni = 0; ni < 4; ni++) {
            int row = wn + ni * 16 + fr;
            int idx = row * 4 + (fs ^ ((row >> 1) & 3));
            bh[ni] = *reinterpret_cast<const bf16x8*>(&sB[0][idx]);
            bl[ni] = *reinterpret_cast<const bf16x8*>(&sB[1][idx]);
        }
        #pragma unroll
        for (int mi = 0; mi < 4; mi++)
            #pragma unroll
            for (int ni = 0; ni < 4; ni++) {
                acc[mi][ni] = __builtin_amdgcn_mfma_f32_16x16x32_bf16(ah[mi], bh[ni], acc[mi][ni], 0, 0, 0);
                acc[mi][ni] = __builtin_amdgcn_mfma_f32_16x16x32_bf16(ah[mi], bl[ni], acc[mi][ni], 0, 0, 0);
                acc[mi][ni] = __builtin_amdgcn_mfma_f32_16x16x32_bf16(al[mi], bh[ni], acc[mi][ni], 0, 0, 0);
            }
        __syncthreads();
    }
    // C/D layout (verified m89): col = lane&15, row = (lane>>4)*4 + reg
    #pragma unroll
    for (int mi = 0; mi < 4; mi++) {
        #pragma unroll
        for (int ni = 0; ni < 4; ni++) {
            int colg = bn + wn + ni * 16 + fr;
            int rbase = bm + wm + mi * 16 + fs * 4;
            #pragma unroll
            for (int r = 0; r < 4; r++) {
                int rw = rbase + r;
                if (rw < M) Cbf[(size_t)rw * N + colg] = (u16)f2bf(acc[mi][ni][r]);
            }
        }
    }
}

// ================= fp32 GEMM for layer 3 (K=128, N=64) -> bf16 out =================
template<int TN>
__launch_bounds__(256)
__global__ void gemm_tile(const float* __restrict__ A, const float* __restrict__ B,
                          u16* __restrict__ Cbf, int M, int K, int N) {
    constexpr int BNt = 16 * TN;
    __shared__ float As[32][132];
    __shared__ float Bs[32][BNt + 4];
    const int bm = blockIdx.y * 128;
    const int bn = blockIdx.x * BNt;
    const int tid = threadIdx.x;
    const int tr = tid >> 4;
    const int tc = tid & 15;
    const int la_m = tid >> 3;
    const int la_k = (tid & 7) << 2;
    const int lb_row = tid / (BNt / 4);
    const int lb_c = (tid % (BNt / 4)) * 4;
    float acc[8][TN] = {};
    for (int k0 = 0; k0 < K; k0 += 32) {
        #pragma unroll
        for (int p = 0; p < 4; p++) {
            int m = la_m + p * 32;
            int gm = bm + m;
            float4 v = make_float4(0.f, 0.f, 0.f, 0.f);
            if (gm < M) v = *reinterpret_cast<const float4*>(&A[(size_t)gm * K + k0 + la_k]);
            As[la_k + 0][m] = v.x;
            As[la_k + 1][m] = v.y;
            As[la_k + 2][m] = v.z;
            As[la_k + 3][m] = v.w;
        }
        #pragma unroll
        for (int p = 0; p < BNt / 32; p++) {
            int kk = lb_row + p * (1024 / BNt);
            *reinterpret_cast<float4*>(&Bs[kk][lb_c]) =
                *reinterpret_cast<const float4*>(&B[(size_t)(k0 + kk) * N + bn + lb_c]);
        }
        __syncthreads();
        #pragma unroll
        for (int kk = 0; kk < 32; kk++) {
            float a[8], b[TN];
            float4 a0 = *reinterpret_cast<const float4*>(&As[kk][tr * 4]);
            float4 a1 = *reinterpret_cast<const float4*>(&As[kk][64 + tr * 4]);
            a[0] = a0.x; a[1] = a0.y; a[2] = a0.z; a[3] = a0.w;
            a[4] = a1.x; a[5] = a1.y; a[6] = a1.z; a[7] = a1.w;
            float4 b0 = *reinterpret_cast<const float4*>(&Bs[kk][tc * 4]);
            b[0] = b0.x; b[1] = b0.y; b[2] = b0.z; b[3] = b0.w;
            if constexpr (TN == 8) {
                float4 b1 = *reinterpret_cast<const float4*>(&Bs[kk][64 + tc * 4]);
                b[4] = b1.x; b[5] = b1.y; b[6] = b1.z; b[7] = b1.w;
            }
            #pragma unroll
            for (int i = 0; i < 8; i++)
                #pragma unroll
                for (int j = 0; j < TN; j++)
                    acc[i][j] += a[i] * b[j];
        }
        __syncthreads();
    }
    #pragma unroll
    for (int i = 0; i < 8; i++) {
        int m = bm + ((i < 4) ? (tr * 4 + i) : (64 + tr * 4 + (i - 4)));
        if (m >= M) continue;
        uint2 p0 = make_uint2(f2bf(acc[i][0]) | (f2bf(acc[i][1]) << 16),
                              f2bf(acc[i][2]) | (f2bf(acc[i][3]) << 16));
        *reinterpret_cast<uint2*>(&Cbf[(size_t)m * N + bn + tc * 4]) = p0;
        if constexpr (TN == 8) {
            uint2 p1 = make_uint2(f2bf(acc[i][4]) | (f2bf(acc[i][5]) << 16),
                                  f2bf(acc[i][6]) | (f2bf(acc[i][7]) << 16));
            *reinterpret_cast<uint2*>(&Cbf[(size_t)m * N + bn + 64 + tc * 4]) = p1;
        }
    }
}

// ================= small GEMM for layer 4: K=64, N=16 -> bf16 out =================
__launch_bounds__(256)
__global__ void gemm_k64n16(const float* __restrict__ A, const float* __restrict__ B,
                            u16* __restrict__ Cbf, int M) {
    __shared__ float As[64][68];
    __shared__ float Bs[64][16];
    const int tid = threadIdx.x;
    const int bm = blockIdx.x * 64;
    {
        int r = tid >> 2, c = (tid & 3) << 2;
        *reinterpret_cast<float4*>(&Bs[r][c]) = *reinterpret_cast<const float4*>(&B[r * 16 + c]);
    }
    #pragma unroll
    for (int p = 0; p < 4; p++) {
        int m = (tid >> 4) + p * 16;
        int c = (tid & 15) << 2;
        int gm = bm + m;
        float4 v = make_float4(0.f, 0.f, 0.f, 0.f);
        if (gm < M) v = *reinterpret_cast<const float4*>(&A[(size_t)gm * 64 + c]);
        *reinterpret_cast<float4*>(&As[m][c]) = v;
    }
    __syncthreads();
    const int tc = tid & 15;
    const int r0 = tid >> 4;
    float acc[4] = {};
    #pragma unroll
    for (int k4 = 0; k4 < 16; k4++) {
        float b0 = Bs[4 * k4 + 0][tc];
        float b1 = Bs[4 * k4 + 1][tc];
        float b2 = Bs[4 * k4 + 2][tc];
        float b3 = Bs[4 * k4 + 3][tc];
        #pragma unroll
        for (int i = 0; i < 4; i++) {
            float4 av = *reinterpret_cast<const float4*>(&As[r0 + i * 16][4 * k4]);
            acc[i] += av.x * b0 + av.y * b1 + av.z * b2 + av.w * b3;
        }
    }
    #pragma unroll
    for (int i = 0; i < 4; i++) {
        int m = bm + r0 + i * 16;
        if (m < M) Cbf[(size_t)m * 16 + tc] = (u16)f2bf(acc[i]);
    }
}

// ================= per-node attention scores (bf16 h) =================
__global__ void scores_kernel(const u16* __restrict__ h,
                              const float* __restrict__ asrc,
                              const float* __restrict__ adst,
                              float* __restrict__ es, float* __restrict__ ed,
                              int Nn, int H, int C) {
    int idx = blockIdx.x * blockDim.x + threadIdx.x;
    if (idx >= Nn * H) return;
    int n = idx / H, hh = idx % H;
    const u16* hp = h + ((size_t)n * H + hh) * C;
    const float4* ap = reinterpret_cast<const float4*>(asrc + hh * C);
    const float4* bp = reinterpret_cast<const float4*>(adst + hh * C);
    float s = 0.f, d = 0.f;
    for (int c4 = 0; c4 < C / 4; c4++) {
        uint2 pv = *reinterpret_cast<const uint2*>(hp + 4 * c4);
        float v0 = bfl(pv.x), v1 = bfh(pv.x), v2 = bfl(pv.y), v3 = bfh(pv.y);
        float4 a = ap[c4], b = bp[c4];
        s += v0 * a.x + v1 * a.y + v2 * a.z + v3 * a.w;
        d += v0 * b.x + v1 * b.y + v2 * b.z + v3 * b.w;
    }
    es[idx] = s;
    ed[idx] = d;
}

// ================= CSR build =================
__global__ void hist_kernel(const int* __restrict__ dst, int* __restrict__ counts,
                            int E0, int Etot) {
    int e = blockIdx.x * blockDim.x + threadIdx.x;
    if (e >= Etot) return;
    int d_ = (e < E0) ? dst[e] : e - E0;
    atomicAdd(&counts[d_], 1);
}

__global__ void scan_kernel(const int* __restrict__ counts, int* __restrict__ row_ptr, int Nn) {
    __shared__ int wsum[16];
    __shared__ int chunk_total;
    __shared__ int carry_s;
    const int tid = threadIdx.x;
    const int lane = tid & 63;
    const int wid = tid >> 6;
    if (tid == 0) carry_s = 0;
    __syncthreads();
    for (int base = 0; base < Nn; base += 1024) {
        int i = base + tid;
        int v = (i < Nn) ? counts[i] : 0;
        int iv = v;
        #pragma unroll
        for (int off = 1; off < 64; off <<= 1) {
            int t = __shfl_up(iv, off, 64);
            if (lane >= off) iv += t;
        }
        if (lane == 63) wsum[wid] = iv;
        __syncthreads();
        if (tid == 0) {
            int s = 0;
            #pragma unroll
            for (int k = 0; k < 16; k++) { int t = wsum[k]; wsum[k] = s; s += t; }
            chunk_total = s;
        }
        __syncthreads();
        if (i < Nn) row_ptr[i] = carry_s + wsum[wid] + (iv - v);
        __syncthreads();
        if (tid == 0) carry_s += chunk_total;
        __syncthreads();
    }
    if (tid == 0) row_ptr[Nn] = carry_s;
}

__global__ void scatter_kernel(const int* __restrict__ src, const int* __restrict__ dst,
                               int* __restrict__ cursor, int* __restrict__ col,
                               int E0, int Etot) {
    int e = blockIdx.x * blockDim.x + threadIdx.x;
    if (e >= Etot) return;
    int d_ = (e < E0) ? dst[e] : e - E0;
    int s_ = (e < E0) ? src[e] : e - E0;
    int pos = atomicAdd(&cursor[d_], 1);
    col[pos] = s_;
}

// ========== fused softmax + aggregate (bf16 h gather) + bias + ELU + BN ==========
template<int H, int C, int NT, int DO_ELU>
__launch_bounds__(256)
__global__ void gat_fused(const int* __restrict__ row_ptr, const int* __restrict__ col,
                          const float* __restrict__ es, const float* __restrict__ ed,
                          const u16* __restrict__ h16, float* __restrict__ out,
                          const float* __restrict__ bias, const float* __restrict__ g,
                          const float* __restrict__ be, const float* __restrict__ rm,
                          const float* __restrict__ rv, int Nn) {
    constexpr int Dout = H * C;
    constexpr int VEC = Dout / NT;
    constexpr int NPB = 256 / NT;
    constexpr int CH = 64;
    __shared__ float w_s[NPB][CH][H];
    __shared__ int   c_s[NPB][CH];
    __shared__ float ed_s[NPB][H];
    __shared__ int   md;
    const int tid = threadIdx.x;
    const int slot = tid / NT;
    const int t = tid % NT;
    const int node = blockIdx.x * NPB + slot;
    const bool alive = node < Nn;
    int jb = 0, je = 0;
    if (alive) { jb = row_ptr[node]; je = row_ptr[node + 1]; }
    if (tid == 0) md = 0;
    __syncthreads();
    if (alive && t == 0) atomicMax(&md, je - jb);
    if (alive && t < H) ed_s[slot][t] = ed[node * H + t];
    __syncthreads();
    const int nch = (md + CH - 1) / CH;
    const int c0 = t * VEC;
    const int hh = c0 / C;
    float acc[VEC] = {};
    float den = 0.f;
    for (int cc = 0; cc < nch; cc++) {
        int j0 = jb + cc * CH;
        int cnt = je - j0;
        if (cnt > CH) cnt = CH;
        if (alive) {
            for (int tt = t; tt < cnt; tt += NT) {
                int s = col[j0 + tt];
                c_s[slot][tt] = s;
                if constexpr (H == 8) {
                    const float4* ep = reinterpret_cast<const float4*>(&es[s * 8]);
                    float4 e0 = ep[0], e1 = ep[1];
                    float al[8] = {e0.x, e0.y, e0.z, e0.w, e1.x, e1.y, e1.z, e1.w};
                    #pragma unroll
                    for (int h2 = 0; h2 < 8; h2++) {
                        float a = al[h2] + ed_s[slot][h2];
                        a = (a >= 0.f) ? a : NEG_SLOPE * a;
                        w_s[slot][tt][h2] = __expf(a);
                    }
                } else {
                    float a = es[s] + ed_s[slot][0];
                    a = (a >= 0.f) ? a : NEG_SLOPE * a;
                    w_s[slot][tt][0] = __expf(a);
                }
            }
        }
        __syncthreads();
        if (alive && cnt > 0) {
            int j = 0;
            if constexpr (VEC == 4) {
                for (; j + 4 <= cnt; j += 4) {
                    int s0 = c_s[slot][j],     s1 = c_s[slot][j + 1];
                    int s2 = c_s[slot][j + 2], s3 = c_s[slot][j + 3];
                    float w0 = w_s[slot][j][hh],     w1 = w_s[slot][j + 1][hh];
                    float w2 = w_s[slot][j + 2][hh], w3 = w_s[slot][j + 3][hh];
                    const uint2 p0 = *reinterpret_cast<const uint2*>(h16 + (size_t)s0 * Dout + c0);
                    const uint2 p1 = *reinterpret_cast<const uint2*>(h16 + (size_t)s1 * Dout + c0);
                    const uint2 p2 = *reinterpret_cast<const uint2*>(h16 + (size_t)s2 * Dout + c0);
                    const uint2 p3 = *reinterpret_cast<const uint2*>(h16 + (size_t)s3 * Dout + c0);
                    den += (w0 + w1) + (w2 + w3);
                    acc[0] += w0 * bfl(p0.x) + w1 * bfl(p1.x) + w2 * bfl(p2.x) + w3 * bfl(p3.x);
                    acc[1] += w0 * bfh(p0.x) + w1 * bfh(p1.x) + w2 * bfh(p2.x) + w3 * bfh(p3.x);
                    acc[2] += w0 * bfl(p0.y) + w1 * bfl(p1.y) + w2 * bfl(p2.y) + w3 * bfl(p3.y);
                    acc[3] += w0 * bfh(p0.y) + w1 * bfh(p1.y) + w2 * bfh(p2.y) + w3 * bfh(p3.y);
                }
            } else if constexpr (VEC == 2) {
                for (; j + 4 <= cnt; j += 4) {
                    int s0 = c_s[slot][j],     s1 = c_s[slot][j + 1];
                    int s2 = c_s[slot][j + 2], s3 = c_s[slot][j + 3];
                    float w0 = w_s[slot][j][hh],     w1 = w_s[slot][j + 1][hh];
                    float w2 = w_s[slot][j + 2][hh], w3 = w_s[slot][j + 3][hh];
                    const u32 p0 = *reinterpret_cast<const u32*>(h16 + (size_t)s0 * Dout + c0);
                    const u32 p1 = *reinterpret_cast<const u32*>(h16 + (size_t)s1 * Dout + c0);
                    const u32 p2 = *reinterpret_cast<const u32*>(h16 + (size_t)s2 * Dout + c0);
                    const u32 p3 = *reinterpret_cast<const u32*>(h16 + (size_t)s3 * Dout + c0);
                    den += (w0 + w1) + (w2 + w3);
                    acc[0] += w0 * bfl(p0) + w1 * bfl(p1) + w2 * bfl(p2) + w3 * bfl(p3);
                    acc[1] += w0 * bfh(p0) + w1 * bfh(p1) + w2 * bfh(p2) + w3 * bfh(p3);
                }
            } else {
                for (; j + 4 <= cnt; j += 4) {
                    int s0 = c_s[slot][j],     s1 = c_s[slot][j + 1];
                    int s2 = c_s[slot][j + 2], s3 = c_s[slot][j + 3];
                    float w0 = w_s[slot][j][hh],     w1 = w_s[slot][j + 1][hh];
                    float w2 = w_s[slot][j + 2][hh], w3 = w_s[slot][j + 3][hh];
                    float v0 = bf2f(h16[(size_t)s0 * Dout + c0]);
                    float v1 = bf2f(h16[(size_t)s1 * Dout + c0]);
                    float v2 = bf2f(h16[(size_t)s2 * Dout + c0]);
                    float v3 = bf2f(h16[(size_t)s3 * Dout + c0]);
                    den += (w0 + w1) + (w2 + w3);
                    acc[0] += w0 * v0 + w1 * v1 + w2 * v2 + w3 * v3;
                }
            }
            for (; j < cnt; j++) {
                float w = w_s[slot][j][hh];
                den += w;
                const u16* hp = h16 + (size_t)c_s[slot][j] * Dout + c0;
                if constexpr (VEC == 4) {
                    const uint2 pv = *reinterpret_cast<const uint2*>(hp);
                    acc[0] += w * bfl(pv.x); acc[1] += w * bfh(pv.x);
                    acc[2] += w * bfl(pv.y); acc[3] += w * bfh(pv.y);
                } else if constexpr (VEC == 2) {
                    const u32 pv = *reinterpret_cast<const u32*>(hp);
                    acc[0] += w * bfl(pv); acc[1] += w * bfh(pv);
                } else {
                    acc[0] += w * bf2f(hp[0]);
                }
            }
        }
        __syncthreads();
    }
    if (!alive) return;
    const float inv = 1.f / (den + 1e-16f);
    float res[VEC];
    #pragma unroll
    for (int v = 0; v < VEC; v++) {
        const int jc = c0 + v;
        float y = acc[v] * inv + bias[jc];
        if (DO_ELU) y = (y > 0.f) ? y : expm1f(y);
        y = (y - rm[jc]) * rsqrtf(rv[jc] + BN_EPS) * g[jc] + be[jc];
        res[v] = y;
    }
    float* op = out + (size_t)node * Dout + c0;
    if constexpr (VEC == 4) {
        *reinterpret_cast<float4*>(op) = make_float4(res[0], res[1], res[2], res[3]);
    } else if constexpr (VEC == 2) {
        *reinterpret_cast<float2*>(op) = make_float2(res[0], res[1]);
    } else {
        op[0] = res[0];
    }
}

extern "C" void kernel_launch(void* const* d_in, const int* in_sizes, int n_in,
                              void* d_out, int out_size, void* d_ws, size_t ws_size,
                              hipStream_t stream) {
    const float* x = (const float*)d_in[0];
    const int* src = (const int*)d_in[1];
    const int* dst = (const int*)d_in[2];
    const int Nn = in_sizes[0] / 128;   // 50000
    const int E0 = in_sizes[1];         // 400000
    const int Etot = E0 + Nn;

    // workspace layout
    float* B0 = (float*)d_ws;                       // Nn*256 f32 region
    float* B1 = B0 + (size_t)Nn * 256;              // Nn*256 f32 region
    float* es = B1 + (size_t)Nn * 256;
    float* ed = es + (size_t)Nn * 8;
    int* row_ptr = (int*)(ed + (size_t)Nn * 8);
    int* cursor  = row_ptr + (Nn + 1);
    int* col     = cursor + Nn;
    u16* wth = (u16*)(col + Etot);                  // up to 256*256
    u16* wtl = wth + 256 * 256;

    // ---- CSR build ----
    hipMemsetAsync(cursor, 0, sizeof(int) * Nn, stream);
    hist_kernel<<<(Etot + 255) / 256, 256, 0, stream>>>(dst, cursor, E0, Etot);
    scan_kernel<<<1, 1024, 0, stream>>>(cursor, row_ptr, Nn);
    hipMemcpyAsync(cursor, row_ptr, sizeof(int) * Nn, hipMemcpyDeviceToDevice, stream);
    scatter_kernel<<<(Etot + 255) / 256, 256, 0, stream>>>(src, dst, cursor, col, E0, Etot);

    const int gy128 = (Nn + 127) / 128;

    for (int l = 0; l < 4; l++) {
        const float* const* p = (const float* const*)(d_in + 3 + l * 8);
        const float* W    = p[0];
        const float* asrc = p[1];
        const float* adst = p[2];
        const float* bias = p[3];
        const float* g    = p[4];
        const float* be   = p[5];
        const float* rm   = p[6];
        const float* rv   = p[7];

        if (l == 0) {
            const int K = 128, N = 256;
            u16* SH = (u16*)B1;
            u16* SL = SH + (size_t)Nn * K;
            int n4 = Nn * K / 4;
            split_kernel<<<(n4 + 255) / 256, 256, 0, stream>>>(
                (const float4*)x, (uint2*)SH, (uint2*)SL, n4);
            wt_prep<<<(K * N + 255) / 256, 256, 0, stream>>>(W, wth, wtl, K, N);
            u16* h1 = (u16*)B0;                       // Nn x 256 bf16
            gemm_mfma<<<dim3(N / 128, gy128), 256, 0, stream>>>(SH, SL, wth, wtl, h1, Nn, K, N);
            scores_kernel<<<(Nn * 8 + 255) / 256, 256, 0, stream>>>(h1, asrc, adst, es, ed, Nn, 8, 32);
            gat_fused<8, 32, 64, 1><<<(Nn + 3) / 4, 256, 0, stream>>>(
                row_ptr, col, es, ed, h1, B1, bias, g, be, rm, rv, Nn);   // out1 -> B1 (fp32)
        } else if (l == 1) {
            const int K = 256, N = 128;
            u16* SH = (u16*)B0;                       // overwrites dead h1
            u16* SL = SH + (size_t)Nn * K;
            int n4 = Nn * K / 4;
            split_kernel<<<(n4 + 255) / 256, 256, 0, stream>>>(
                (const float4*)B1, (uint2*)SH, (uint2*)SL, n4);
            wt_prep<<<(K * N + 255) / 256, 256, 0, stream>>>(W, wth, wtl, K, N);
            u16* h2 = (u16*)B1;                       // Nn x 128 bf16 (overwrites dead out1)
            float* out2 = B1 + (size_t)Nn * 64;       // fp32 Nn x 128, after h2 region
            gemm_mfma<<<dim3(N / 128, gy128), 256, 0, stream>>>(SH, SL, wth, wtl, h2, Nn, K, N);
            scores_kernel<<<(Nn * 8 + 255) / 256, 256, 0, stream>>>(h2, asrc, adst, es, ed, Nn, 8, 16);
            gat_fused<8, 16, 64, 1><<<(Nn + 3) / 4, 256, 0, stream>>>(
                row_ptr, col, es, ed, h2, out2, bias, g, be, rm, rv, Nn);
        } else if (l == 2) {
            const float* in = B1 + (size_t)Nn * 64;   // out2
            u16* h3 = (u16*)B0;                        // Nn x 64 bf16
            float* out3 = B0 + (size_t)Nn * 32;        // fp32 Nn x 64, after h3 region
            gemm_tile<4><<<dim3(1, gy128), 256, 0, stream>>>(in, W, h3, Nn, 128, 64);
            scores_kernel<<<(Nn * 8 + 255) / 256, 256, 0, stream>>>(h3, asrc, adst, es, ed, Nn, 8, 8);
            gat_fused<8, 8, 64, 1><<<(Nn + 3) / 4, 256, 0, stream>>>(
                row_ptr, col, es, ed, h3, out3, bias, g, be, rm, rv, Nn);
        } else {
            const float* in = B0 + (size_t)Nn * 32;   // out3
            u16* h4 = (u16*)B1;                        // Nn x 16 bf16
            gemm_k64n16<<<(Nn + 63) / 64, 256, 0, stream>>>(in, W, h4, Nn);
            scores_kernel<<<(Nn + 255) / 256, 256, 0, stream>>>(h4, asrc, adst, es, ed, Nn, 1, 16);
            gat_fused<1, 16, 16, 0><<<(Nn + 15) / 16, 256, 0, stream>>>(
                row_ptr, col, es, ed, h4, (float*)d_out, bias, g, be, rm, rv, Nn);
        }
    }
}